// Round 3
// baseline (130.047 us; speedup 1.0000x reference)
//
#include <hip/hip_runtime.h>

#define NROWS 131072
#define DDIM  64
#define KCTR  512
#define OUT_W 577           /* 1 + 64 + 512 */
#define K_HALF_LN2 0.34657359027997264f   /* 0.5*ln(2) */

typedef __attribute__((ext_vector_type(8))) short bfrag8;
typedef __attribute__((ext_vector_type(4))) float f32x4;
typedef __attribute__((ext_vector_type(2))) float f32x2;

// 16B vector store with only 4B alignment guarantee (out rows are 2308B-strided).
struct __attribute__((packed, aligned(4))) F4a4 { f32x4 v; };

__device__ __forceinline__ short f2bf(float f) {
    union { float f; unsigned u; } v; v.f = f;
    return (short)((v.u + 0x8000u) >> 16);   // round-to-nearest (ties away)
}

// Prep: center squared norms (f32) + centers converted to bf16, into d_ws.
__global__ __launch_bounds__(256) void prep_kernel(
    const float* __restrict__ centers, float* __restrict__ cnorm,
    short* __restrict__ cbf)
{
    int k = blockIdx.x * 256 + threadIdx.x;
    if (k >= KCTR) return;
    const float* c = centers + (size_t)k * DDIM;
    short* o = cbf + (size_t)k * DDIM;
    float s = 0.f;
#pragma unroll
    for (int i0 = 0; i0 < DDIM; i0 += 8) {
        bfrag8 b;
#pragma unroll
        for (int j = 0; j < 8; ++j) {
            float v = c[i0 + j];
            s += v * v;
            b[j] = f2bf(v);
        }
        *reinterpret_cast<bfrag8*>(o + i0) = b;
    }
    cnorm[k] = s;
}

// Main: block = 32 data rows x all 512 centers. 4 waves; wave w owns centers
// [w*128, w*128+128) x 32 rows. MFMA operands: A = centers (M), B = data (N),
// so D regs map to 4 consecutive center cols -> one 16B store per (mf,nf).
__global__ __launch_bounds__(256) void dicrbf_mfma(
    const float* __restrict__ data,
    const float* __restrict__ cnorm_g,
    const short* __restrict__ cbf,
    float* __restrict__ out)
{
    __shared__ float s_cnorm[KCTR];
    __shared__ float s_xsq[32];
    __shared__ short s_dbf[32][72];   // bf16 data tile, stride 144B (bank-spread)

    const int t = threadIdx.x;
    const int row0 = blockIdx.x * 32;

    // cnorm -> LDS (2 floats/thread)
    {
        f32x2 c = *reinterpret_cast<const f32x2*>(cnorm_g + 2 * t);
        *reinterpret_cast<f32x2*>(&s_cnorm[2 * t]) = c;
    }

    // Phase 1: single pass over this block's data rows.
    // thread -> (row r = t>>3, 8-col chunk j = t&7)
    {
        const int r = t >> 3, j = t & 7;
        const float* src = data + (size_t)(row0 + r) * DDIM + j * 8;
        const f32x4 v0 = *reinterpret_cast<const f32x4*>(src);
        const f32x4 v1 = *reinterpret_cast<const f32x4*>(src + 4);

        // partial sum of squares -> 8-lane reduce -> s_xsq
        float s = v0[0]*v0[0] + v0[1]*v0[1] + v0[2]*v0[2] + v0[3]*v0[3]
                + v1[0]*v1[0] + v1[1]*v1[1] + v1[2]*v1[2] + v1[3]*v1[3];
        s += __shfl_xor(s, 1);
        s += __shfl_xor(s, 2);
        s += __shfl_xor(s, 4);
        if (j == 0) s_xsq[r] = s;

        // bf16 conversion -> LDS tile (one ds_write_b128)
        bfrag8 b;
        b[0] = f2bf(v0[0]); b[1] = f2bf(v0[1]); b[2] = f2bf(v0[2]); b[3] = f2bf(v0[3]);
        b[4] = f2bf(v1[0]); b[5] = f2bf(v1[1]); b[6] = f2bf(v1[2]); b[7] = f2bf(v1[3]);
        *reinterpret_cast<bfrag8*>(&s_dbf[r][j * 8]) = b;

        // passthrough + ones
        float* orow = out + (size_t)(row0 + r) * OUT_W;
        reinterpret_cast<F4a4*>(orow + 1 + j * 8)->v = v0;
        reinterpret_cast<F4a4*>(orow + 1 + j * 8 + 4)->v = v1;
        if (j == 0) orow[0] = 1.0f;
    }
    __syncthreads();

    const int lane = t & 63;
    const int wid  = t >> 6;
    const int l15  = lane & 15;
    const int lhi  = lane >> 4;
    const int cbase = wid * 128;

    // B fragments (data rows) from LDS: col = l15 -> row nf*16+l15, k = ks*32+lhi*8+j
    bfrag8 bfr[2][2];
#pragma unroll
    for (int nf = 0; nf < 2; ++nf)
#pragma unroll
        for (int ks = 0; ks < 2; ++ks)
            bfr[nf][ks] = *reinterpret_cast<const bfrag8*>(
                &s_dbf[nf * 16 + l15][ks * 32 + lhi * 8]);

    const float xsq0 = s_xsq[l15];
    const float xsq1 = s_xsq[16 + l15];

#pragma unroll
    for (int mf = 0; mf < 8; ++mf) {
        // A fragments (centers): row = l15 -> center cbase+mf*16+l15
        const short* ap = cbf + (size_t)(cbase + mf * 16 + l15) * DDIM + lhi * 8;
        const bfrag8 a0 = *reinterpret_cast<const bfrag8*>(ap);        // k 0..31
        const bfrag8 a1 = *reinterpret_cast<const bfrag8*>(ap + 32);   // k 32..63

        f32x4 acc0 = (f32x4)(0.f);
        f32x4 acc1 = (f32x4)(0.f);
        acc0 = __builtin_amdgcn_mfma_f32_16x16x32_bf16(a0, bfr[0][0], acc0, 0, 0, 0);
        acc0 = __builtin_amdgcn_mfma_f32_16x16x32_bf16(a1, bfr[0][1], acc0, 0, 0, 0);
        acc1 = __builtin_amdgcn_mfma_f32_16x16x32_bf16(a0, bfr[1][0], acc1, 0, 0, 0);
        acc1 = __builtin_amdgcn_mfma_f32_16x16x32_bf16(a1, bfr[1][1], acc1, 0, 0, 0);

        // center norms for this lane's 4 output cols (16B LDS read)
        const f32x4 cn4 = *reinterpret_cast<const f32x4*>(
            &s_cnorm[cbase + mf * 16 + lhi * 4]);

        // Epilogue: d2 = xsq + cn - 2*dot ; rbf ~= 0.5*ln2 * d2 * log2(d2)
#pragma unroll
        for (int nf = 0; nf < 2; ++nf) {
            const float xs = nf ? xsq1 : xsq0;
            const f32x4 ac = nf ? acc1 : acc0;
            f32x4 rv;
#pragma unroll
            for (int k = 0; k < 4; ++k) {
                float d2 = xs + cn4[k] - 2.0f * ac[k];
                d2 = fmaxf(d2, 0.0f);
                float v = (K_HALF_LN2 * d2) * __log2f(d2);
                rv[k] = (d2 > 0.0f) ? v : 0.0f;
            }
            float* p = out + (size_t)(row0 + nf * 16 + l15) * OUT_W
                     + 1 + DDIM + cbase + mf * 16 + lhi * 4;
            reinterpret_cast<F4a4*>(p)->v = rv;
        }
    }
}

extern "C" void kernel_launch(void* const* d_in, const int* in_sizes, int n_in,
                              void* d_out, int out_size, void* d_ws, size_t ws_size,
                              hipStream_t stream) {
    const float* data    = (const float*)d_in[0];
    const float* centers = (const float*)d_in[1];
    float* out = (float*)d_out;

    float* cnorm = (float*)d_ws;                     // 512 f32 = 2 KB
    short* cbf   = (short*)((char*)d_ws + 2048);     // 512*64 bf16 = 64 KB

    hipLaunchKernelGGL(prep_kernel, dim3(2), dim3(256), 0, stream, centers, cnorm, cbf);
    hipLaunchKernelGGL(dicrbf_mfma, dim3(NROWS / 32), dim3(256), 0, stream,
                       data, cnorm, cbf, out);
}

// Round 4
// 116.945 us; speedup vs baseline: 1.1120x; 1.1120x over previous
//
#include <hip/hip_runtime.h>

#define NROWS 131072
#define DDIM  64
#define KCTR  512
#define OUT_W 577                 /* 1 + 64 + 512 */
#define ROWS_PER_BLOCK 16
#define SPAN_F32 (ROWS_PER_BLOCK * OUT_W)        /* 9232 floats = 36928 B */
#define SPAN_V4  (SPAN_F32 / 4)                  /* 2308 */
#define K_HALF_LN2 0.34657359027997264f          /* 0.5*ln(2) */

typedef __attribute__((ext_vector_type(8))) short bfrag8;
typedef __attribute__((ext_vector_type(4))) float f32x4;

__device__ __forceinline__ short f2bf(float f) {
    union { float f; unsigned u; } v; v.f = f;
    return (short)((v.u + 0x8000u) >> 16);   // round-to-nearest
}

// Prep: center squared norms (f32) + centers converted to bf16, into d_ws.
__global__ __launch_bounds__(256) void prep_kernel(
    const float* __restrict__ centers, float* __restrict__ cnorm,
    short* __restrict__ cbf)
{
    int k = blockIdx.x * 256 + threadIdx.x;
    if (k >= KCTR) return;
    const float* c = centers + (size_t)k * DDIM;
    short* o = cbf + (size_t)k * DDIM;
    float s = 0.f;
#pragma unroll
    for (int i0 = 0; i0 < DDIM; i0 += 8) {
        bfrag8 b;
#pragma unroll
        for (int j = 0; j < 8; ++j) {
            float v = c[i0 + j];
            s += v * v;
            b[j] = f2bf(v);
        }
        *reinterpret_cast<bfrag8*>(o + i0) = b;
    }
    cnorm[k] = s;
}

// Main: block = 16 data rows x all 512 centers. Entire 36928B output span is
// built in LDS, then streamed out with aligned, fully-coalesced dwordx4 stores
// (one full 64B line per 4 lanes, each line written exactly once).
__global__ __launch_bounds__(256) void dicrbf_mfma(
    const float* __restrict__ data,
    const float* __restrict__ cnorm_g,
    const short* __restrict__ cbf,
    float* __restrict__ out)
{
    __shared__ __align__(16) float s_span[SPAN_F32];   // 36928 B
    __shared__ short s_dbf[ROWS_PER_BLOCK][80];        // bf16 data tile, 2560 B
    __shared__ float s_xsq[ROWS_PER_BLOCK];

    const int t = threadIdx.x;
    const int row0 = blockIdx.x * ROWS_PER_BLOCK;

    // ---- Phase 1: one pass over the block's 16 data rows (16 thr/row) ----
    {
        const int r = t >> 4, j = t & 15;          // 4 floats per thread
        const f32x4 v = *reinterpret_cast<const f32x4*>(
            data + (size_t)(row0 + r) * DDIM + j * 4);

        float s = v[0]*v[0] + v[1]*v[1] + v[2]*v[2] + v[3]*v[3];
        s += __shfl_xor(s, 1);
        s += __shfl_xor(s, 2);
        s += __shfl_xor(s, 4);
        s += __shfl_xor(s, 8);
        if (j == 0) { s_xsq[r] = s; s_span[r * OUT_W] = 1.0f; }

        // f32 passthrough into the span (cols 1..64)
        float* sp = &s_span[r * OUT_W + 1 + j * 4];
        sp[0] = v[0]; sp[1] = v[1]; sp[2] = v[2]; sp[3] = v[3];

        // bf16 copy for MFMA B operand (8B aligned store)
        short b4[4] = { f2bf(v[0]), f2bf(v[1]), f2bf(v[2]), f2bf(v[3]) };
        *reinterpret_cast<uint2*>(&s_dbf[r][j * 4]) =
            *reinterpret_cast<const uint2*>(b4);
    }
    __syncthreads();

    const int lane = t & 63;
    const int wid  = t >> 6;
    const int l15  = lane & 15;
    const int lhi  = lane >> 4;
    const int cbase = wid * 128;     // wave's 128 centers

    // B fragments (data rows): row = l15, k = ks*32 + lhi*8 + j
    bfrag8 bfr[2];
#pragma unroll
    for (int ks = 0; ks < 2; ++ks)
        bfr[ks] = *reinterpret_cast<const bfrag8*>(&s_dbf[l15][ks * 32 + lhi * 8]);

    const float xsq = s_xsq[l15];

#pragma unroll
    for (int mf = 0; mf < 8; ++mf) {
        // A fragments (centers) straight from L2-resident cbf
        const short* ap = cbf + (size_t)(cbase + mf * 16 + l15) * DDIM + lhi * 8;
        const bfrag8 a0 = *reinterpret_cast<const bfrag8*>(ap);        // k 0..31
        const bfrag8 a1 = *reinterpret_cast<const bfrag8*>(ap + 32);   // k 32..63

        f32x4 acc = (f32x4)(0.f);
        acc = __builtin_amdgcn_mfma_f32_16x16x32_bf16(a0, bfr[0], acc, 0, 0, 0);
        acc = __builtin_amdgcn_mfma_f32_16x16x32_bf16(a1, bfr[1], acc, 0, 0, 0);

        // D layout: col(l15) = data row, row(lhi*4+reg) = center within mf tile
        const f32x4 cn4 = *reinterpret_cast<const f32x4*>(
            cnorm_g + cbase + mf * 16 + lhi * 4);

        float* sp = &s_span[l15 * OUT_W + 1 + DDIM + cbase + mf * 16 + lhi * 4];
#pragma unroll
        for (int k = 0; k < 4; ++k) {
            float d2 = xsq + cn4[k] - 2.0f * acc[k];
            d2 = fmaxf(d2, 0.0f);
            float v = (K_HALF_LN2 * d2) * __log2f(d2);
            sp[k] = (d2 > 0.0f) ? v : 0.0f;
        }
    }
    __syncthreads();

    // ---- Phase 3: stream the span out, aligned + fully coalesced ----
    const f32x4* sp4 = reinterpret_cast<const f32x4*>(s_span);
    f32x4* o4 = reinterpret_cast<f32x4*>(out) + (size_t)blockIdx.x * SPAN_V4;
#pragma unroll 1
    for (int i = t; i < SPAN_V4; i += 256)
        o4[i] = sp4[i];
}

extern "C" void kernel_launch(void* const* d_in, const int* in_sizes, int n_in,
                              void* d_out, int out_size, void* d_ws, size_t ws_size,
                              hipStream_t stream) {
    const float* data    = (const float*)d_in[0];
    const float* centers = (const float*)d_in[1];
    float* out = (float*)d_out;

    float* cnorm = (float*)d_ws;                     // 512 f32 = 2 KB
    short* cbf   = (short*)((char*)d_ws + 2048);     // 512*64 bf16 = 64 KB

    hipLaunchKernelGGL(prep_kernel, dim3(2), dim3(256), 0, stream, centers, cnorm, cbf);
    hipLaunchKernelGGL(dicrbf_mfma, dim3(NROWS / ROWS_PER_BLOCK), dim3(256), 0, stream,
                       data, cnorm, cbf, out);
}

// Round 5
// 93.373 us; speedup vs baseline: 1.3928x; 1.2525x over previous
//
#include <hip/hip_runtime.h>

#define NROWS 131072
#define DDIM  64
#define KCTR  512
#define OUT_W 577                 /* 1 + 64 + 512 */
#define RPB   16                  /* rows per tile */
#define NTILES (NROWS / RPB)      /* 8192 */
#define SPAN_F32 (RPB * OUT_W)    /* 9232 floats = 36928 B */
#define SPAN_V4  (SPAN_F32 / 4)   /* 2308 */
#define GRID 768                  /* 3 blocks/CU x 256 CU, persistent */
#define K_HALF_LN2 0.34657359027997264f   /* 0.5*ln(2) */

typedef __attribute__((ext_vector_type(8))) short bfrag8;
typedef __attribute__((ext_vector_type(4))) float f32x4;

__device__ __forceinline__ short f2bf(float f) {
    union { float f; unsigned u; } v; v.f = f;
    return (short)((v.u + 0x8000u) >> 16);   // round-to-nearest
}

// Single persistent kernel. Per block: centers (A-fragments + norms) live in
// registers for the whole kernel; grid-stride over row tiles with next-tile
// data prefetch; output built in an LDS span and streamed out fully coalesced.
__global__ __launch_bounds__(256, 3) void dicrbf_mfma(
    const float* __restrict__ data,
    const float* __restrict__ centers,
    float* __restrict__ out)
{
    __shared__ __align__(16) float s_span[SPAN_F32];   // 36928 B
    __shared__ short s_dbf[RPB][72];                   // bf16 data tile, 2304 B
    __shared__ float s_xsq[RPB];
    __shared__ float s_cnorm[KCTR];                    // 2 KB

    const int t    = threadIdx.x;
    const int lane = t & 63;
    const int wid  = t >> 6;
    const int l15  = lane & 15;
    const int lhi  = lane >> 4;
    const int cbase = wid * 128;          // this wave's 128 centers

    // ---- Prologue A: center norms (f32 exact) -> LDS, cooperatively ----
    for (int k = t; k < KCTR; k += 256) {
        const f32x4* c4 = reinterpret_cast<const f32x4*>(centers + (size_t)k * DDIM);
        float s = 0.f;
#pragma unroll
        for (int i = 0; i < DDIM / 4; ++i) {
            f32x4 u = c4[i];
            s += u[0]*u[0] + u[1]*u[1] + u[2]*u[2] + u[3]*u[3];
        }
        s_cnorm[k] = s;
    }

    // ---- Prologue B: A-fragments (centers, bf16) -> registers, loop-invariant
    // lane (l15, lhi) holds center row cbase+mf*16+l15, cols ks*32+lhi*8..+7
    bfrag8 afr[8][2];
#pragma unroll
    for (int mf = 0; mf < 8; ++mf) {
        const float* cp = centers + (size_t)(cbase + mf * 16 + l15) * DDIM + lhi * 8;
#pragma unroll
        for (int ks = 0; ks < 2; ++ks) {
            const f32x4 u0 = *reinterpret_cast<const f32x4*>(cp + ks * 32);
            const f32x4 u1 = *reinterpret_cast<const f32x4*>(cp + ks * 32 + 4);
            bfrag8 fr;
            fr[0] = f2bf(u0[0]); fr[1] = f2bf(u0[1]); fr[2] = f2bf(u0[2]); fr[3] = f2bf(u0[3]);
            fr[4] = f2bf(u1[0]); fr[5] = f2bf(u1[1]); fr[6] = f2bf(u1[2]); fr[7] = f2bf(u1[3]);
            afr[mf][ks] = fr;
        }
    }
    __syncthreads();

    // per-lane center norms (4 consecutive centers per mf) -> registers
    f32x4 cnr[8];
#pragma unroll
    for (int mf = 0; mf < 8; ++mf)
        cnr[mf] = *reinterpret_cast<const f32x4*>(&s_cnorm[cbase + mf * 16 + lhi * 4]);

    // ---- Persistent tile loop with next-tile prefetch ----
    const int r  = t >> 4;      // row within tile
    const int jj = t & 15;      // 4-float chunk within row

    size_t tile = blockIdx.x;
    f32x4 v;
    if (tile < NTILES)
        v = *reinterpret_cast<const f32x4*>(data + (tile * RPB + r) * DDIM + jj * 4);

    for (; tile < NTILES; tile += GRID) {
        __syncthreads();   // (1) prev store-phase LDS reads are done

        // P1: xsq reduce + passthrough into span + bf16 tile
        float s = v[0]*v[0] + v[1]*v[1] + v[2]*v[2] + v[3]*v[3];
        s += __shfl_xor(s, 1);
        s += __shfl_xor(s, 2);
        s += __shfl_xor(s, 4);
        s += __shfl_xor(s, 8);
        if (jj == 0) { s_xsq[r] = s; s_span[r * OUT_W] = 1.0f; }

        float* spv = &s_span[r * OUT_W + 1 + jj * 4];
        spv[0] = v[0]; spv[1] = v[1]; spv[2] = v[2]; spv[3] = v[3];

        short b4[4] = { f2bf(v[0]), f2bf(v[1]), f2bf(v[2]), f2bf(v[3]) };
        *reinterpret_cast<uint2*>(&s_dbf[r][jj * 4]) =
            *reinterpret_cast<const uint2*>(b4);

        // prefetch next tile's data (latency hides under P2+P3)
        {
            const size_t nt = tile + GRID;
            if (nt < NTILES)
                v = *reinterpret_cast<const f32x4*>(data + (nt * RPB + r) * DDIM + jj * 4);
        }
        __syncthreads();   // (2) dbf/xsq/span-passthrough ready

        // P2: MFMA + epilogue into span
        const bfrag8 b0 = *reinterpret_cast<const bfrag8*>(&s_dbf[l15][lhi * 8]);
        const bfrag8 b1 = *reinterpret_cast<const bfrag8*>(&s_dbf[l15][32 + lhi * 8]);
        const float xsq = s_xsq[l15];

#pragma unroll
        for (int mf = 0; mf < 8; ++mf) {
            f32x4 acc = (f32x4)(0.f);
            acc = __builtin_amdgcn_mfma_f32_16x16x32_bf16(afr[mf][0], b0, acc, 0, 0, 0);
            acc = __builtin_amdgcn_mfma_f32_16x16x32_bf16(afr[mf][1], b1, acc, 0, 0, 0);

            // D layout: col(l15) = data row, reg k -> center cbase+mf*16+lhi*4+k
            float* sp = &s_span[l15 * OUT_W + 1 + DDIM + cbase + mf * 16 + lhi * 4];
#pragma unroll
            for (int k = 0; k < 4; ++k) {
                float d2 = xsq + cnr[mf][k] - 2.0f * acc[k];
                d2 = fmaxf(d2, 0.0f);
                float w = (K_HALF_LN2 * d2) * __log2f(d2);
                sp[k] = (d2 > 0.0f) ? w : 0.0f;
            }
        }
        __syncthreads();   // (3) span fully written

        // P3: stream span out — aligned, fully-coalesced, each line once
        const f32x4* sp4 = reinterpret_cast<const f32x4*>(s_span);
        f32x4* o4 = reinterpret_cast<f32x4*>(out) + tile * (size_t)SPAN_V4;
#pragma unroll 1
        for (int i = t; i < SPAN_V4; i += 256)
            o4[i] = sp4[i];
    }
}

extern "C" void kernel_launch(void* const* d_in, const int* in_sizes, int n_in,
                              void* d_out, int out_size, void* d_ws, size_t ws_size,
                              hipStream_t stream) {
    const float* data    = (const float*)d_in[0];
    const float* centers = (const float*)d_in[1];
    float* out = (float*)d_out;

    hipLaunchKernelGGL(dicrbf_mfma, dim3(GRID), dim3(256), 0, stream,
                       data, centers, out);
}

// Round 6
// 85.340 us; speedup vs baseline: 1.5239x; 1.0941x over previous
//
#include <hip/hip_runtime.h>

#define NROWS 131072
#define DDIM  64
#define KCTR  512
#define OUT_W 577                 /* 1 + 64 + 512 */
#define RPB   16                  /* rows per tile */
#define NTILES (NROWS / RPB)      /* 8192 */
#define SPAN_F32 (RPB * OUT_W)    /* 9232 floats = 36928 B */
#define SPAN_V4  (SPAN_F32 / 4)   /* 2308 */
#define GRID 512                  /* 2 blocks/CU x 256 CU, persistent */
#define ROUNDS (NTILES / GRID)    /* 16, exact */
#define K_HALF_LN2 0.34657359027997264f   /* 0.5*ln(2) */

typedef __attribute__((ext_vector_type(8))) short bfrag8;
typedef __attribute__((ext_vector_type(4))) float f32x4;

__device__ __forceinline__ short f2bf(float f) {
    union { float f; unsigned u; } v; v.f = f;
    return (short)((v.u + 0x8000u) >> 16);   // round-to-nearest
}

// __syncthreads minus the vmcnt(0) drain: waits only LDS ops, leaves global
// stores in flight across the barrier (m139/m201-verified technique).
__device__ __forceinline__ void lds_barrier() {
    asm volatile("s_waitcnt lgkmcnt(0)" ::: "memory");
    __builtin_amdgcn_s_barrier();
    __builtin_amdgcn_sched_barrier(0);
}

__global__ __launch_bounds__(256, 2) void dicrbf_mfma(
    const float* __restrict__ data,
    const float* __restrict__ centers,
    float* __restrict__ out)
{
    __shared__ __align__(16) float s_span[2][SPAN_F32];  // 73856 B, double-buffered
    __shared__ short s_dbf[RPB][72];                     // bf16 data tile
    __shared__ float s_xsq[RPB];
    __shared__ float s_cnorm[KCTR];

    const int t    = threadIdx.x;
    const int lane = t & 63;
    const int wid  = t >> 6;
    const int l15  = lane & 15;
    const int lhi  = lane >> 4;
    const int cbase = wid * 128;          // this wave's 128 centers

    // ---- Prologue A: center norms (f32 exact) -> LDS ----
    for (int k = t; k < KCTR; k += 256) {
        const f32x4* c4 = reinterpret_cast<const f32x4*>(centers + (size_t)k * DDIM);
        float s = 0.f;
#pragma unroll
        for (int i = 0; i < DDIM / 4; ++i) {
            f32x4 u = c4[i];
            s += u[0]*u[0] + u[1]*u[1] + u[2]*u[2] + u[3]*u[3];
        }
        s_cnorm[k] = s;
    }

    // ---- Prologue B: A-fragments (centers, bf16) -> registers (loop-invariant)
    bfrag8 afr[8][2];
#pragma unroll
    for (int mf = 0; mf < 8; ++mf) {
        const float* cp = centers + (size_t)(cbase + mf * 16 + l15) * DDIM + lhi * 8;
#pragma unroll
        for (int ks = 0; ks < 2; ++ks) {
            const f32x4 u0 = *reinterpret_cast<const f32x4*>(cp + ks * 32);
            const f32x4 u1 = *reinterpret_cast<const f32x4*>(cp + ks * 32 + 4);
            bfrag8 fr;
            fr[0] = f2bf(u0[0]); fr[1] = f2bf(u0[1]); fr[2] = f2bf(u0[2]); fr[3] = f2bf(u0[3]);
            fr[4] = f2bf(u1[0]); fr[5] = f2bf(u1[1]); fr[6] = f2bf(u1[2]); fr[7] = f2bf(u1[3]);
            afr[mf][ks] = fr;
        }
    }
    __syncthreads();   // one-time; vmcnt drain harmless here

    f32x4 cnr[8];
#pragma unroll
    for (int mf = 0; mf < 8; ++mf)
        cnr[mf] = *reinterpret_cast<const f32x4*>(&s_cnorm[cbase + mf * 16 + lhi * 4]);

    // ---- Persistent tile loop; stores never drained inside the loop ----
    const int r  = t >> 4;      // row within tile
    const int jj = t & 15;      // 4-float chunk within row

    size_t tile = blockIdx.x;
    f32x4 v = *reinterpret_cast<const f32x4*>(data + (tile * RPB + r) * DDIM + jj * 4);

    int p = 0;
    for (int round = 0; round < ROUNDS; ++round, tile += GRID, p ^= 1) {
        float* span = s_span[p];

        // P1: xsq reduce + passthrough + bf16 tile; prefetch next tile
        float s = v[0]*v[0] + v[1]*v[1] + v[2]*v[2] + v[3]*v[3];
        s += __shfl_xor(s, 1);
        s += __shfl_xor(s, 2);
        s += __shfl_xor(s, 4);
        s += __shfl_xor(s, 8);
        if (jj == 0) { s_xsq[r] = s; span[r * OUT_W] = 1.0f; }

        float* spv = &span[r * OUT_W + 1 + jj * 4];
        spv[0] = v[0]; spv[1] = v[1]; spv[2] = v[2]; spv[3] = v[3];

        short b4[4] = { f2bf(v[0]), f2bf(v[1]), f2bf(v[2]), f2bf(v[3]) };
        *reinterpret_cast<uint2*>(&s_dbf[r][jj * 4]) =
            *reinterpret_cast<const uint2*>(b4);

        if (round + 1 < ROUNDS)
            v = *reinterpret_cast<const f32x4*>(
                data + ((tile + GRID) * RPB + r) * DDIM + jj * 4);

        lds_barrier();   // dbf/xsq/passthrough visible

        // P2: MFMA + epilogue into span
        const bfrag8 b0 = *reinterpret_cast<const bfrag8*>(&s_dbf[l15][lhi * 8]);
        const bfrag8 b1 = *reinterpret_cast<const bfrag8*>(&s_dbf[l15][32 + lhi * 8]);
        const float xsq = s_xsq[l15];

#pragma unroll
        for (int mf = 0; mf < 8; ++mf) {
            f32x4 acc = (f32x4)(0.f);
            acc = __builtin_amdgcn_mfma_f32_16x16x32_bf16(afr[mf][0], b0, acc, 0, 0, 0);
            acc = __builtin_amdgcn_mfma_f32_16x16x32_bf16(afr[mf][1], b1, acc, 0, 0, 0);

            float* sp = &span[l15 * OUT_W + 1 + DDIM + cbase + mf * 16 + lhi * 4];
#pragma unroll
            for (int k = 0; k < 4; ++k) {
                float d2 = xsq + cnr[mf][k] - 2.0f * acc[k];
                d2 = fmaxf(d2, 0.0f);
                float w = (K_HALF_LN2 * d2) * __log2f(d2);
                sp[k] = (d2 > 0.0f) ? w : 0.0f;
            }
        }

        lds_barrier();   // span fully written

        // P3: stream span out (aligned, fully coalesced); no drain afterwards —
        // stores ride across the next rounds' barriers.
        const f32x4* sp4 = reinterpret_cast<const f32x4*>(span);
        f32x4* o4 = reinterpret_cast<f32x4*>(out) + tile * (size_t)SPAN_V4;
#pragma unroll
        for (int i = 0; i < 9; ++i) {
            const int idx = t + i * 256;
            o4[idx] = sp4[idx];
        }
        if (t < SPAN_V4 - 9 * 256)          // 4 leftover vec4s
            o4[t + 9 * 256] = sp4[t + 9 * 256];
    }
}

extern "C" void kernel_launch(void* const* d_in, const int* in_sizes, int n_in,
                              void* d_out, int out_size, void* d_ws, size_t ws_size,
                              hipStream_t stream) {
    const float* data    = (const float*)d_in[0];
    const float* centers = (const float*)d_in[1];
    float* out = (float*)d_out;

    hipLaunchKernelGGL(dicrbf_mfma, dim3(GRID), dim3(256), 0, stream,
                       data, centers, out);
}